// Round 8
// baseline (6286.088 us; speedup 1.0000x reference)
//
#include <hip/hip_runtime.h>
#include <math.h>

#define NV 50000
#define NB 2048
#define NKEEP 65          // K+1
#define RADIUS_F 0.2f

#define FPS_NBLK 4
#define FPS_NTHR 512
#define PTS_PER 25        // 4*512*25 = 51200 >= 50000
#define FPS_STRIDE (FPS_NBLK * FPS_NTHR)   // 2048
#define SLOT_U64 16       // 128 B per slot: each block's slot on its own LLC line

#define ROW_THR 256
#define CAP 5120          // all-in-radius candidate buffer per row (LDS)
#define CAP2 512          // sub-compacted (b<=kbin) buffer

struct F3 { float x, y, z; };

// ---------------- no-contract arithmetic helpers ----------------

static __device__ __forceinline__ float sn_nc(float x, float y, float z) {
#pragma clang fp contract(off)
  return (x * x + y * y) + z * z;
}

static __device__ __forceinline__ float d2_nc(float ax, float ay, float az,
                                              float bx, float by, float bz) {
#pragma clang fp contract(off)
  float dx = ax - bx, dy = ay - by, dz = az - bz;
  return (dx * dx + dy * dy) + dz * dz;
}

static __device__ __forceinline__ float tval_nc(float cx, float cy, float cz,
                                                float px, float py, float pz,
                                                float pw) {
#pragma clang fp contract(off)
  float gd = (cx * px + cy * py) + cz * pz;
  return (pw - 2.0f * gd) + pw;
}

// ---------------- helpers ----------------

// word0 key = [gen:16 | d2bits:32 | (0xFFFF - idx):16]; d2>=0 so float bits are
// order-monotone; ties -> smaller idx wins (matches jnp.argmax)
static __device__ __forceinline__ unsigned long long pack_key(int gen, float v, unsigned idx) {
  return ((unsigned long long)(unsigned)gen << 48) |
         ((unsigned long long)__float_as_uint(v) << 16) |
         (unsigned long long)(0xFFFFu - idx);
}

static __device__ __forceinline__ unsigned long long wave_max(unsigned long long k) {
#pragma unroll
  for (int m = 1; m < 64; m <<= 1) {
    unsigned long long o = __shfl_xor(k, m, 64);
    if (o > k) k = o;
  }
  return k;
}

#define KEY_NOTREADY 0xFFFF000000000000ull

// ---------------- kernel 0: pack (x,y,z,sn) + init slots ----------------

__global__ void k_init(const float* __restrict__ vtx, float4* __restrict__ pts,
                       int* __restrict__ cidx, unsigned long long* __restrict__ slots) {
  int i = blockIdx.x * blockDim.x + threadIdx.x;
  if (i < NV) {
    float x = vtx[3 * i], y = vtx[3 * i + 1], z = vtx[3 * i + 2];
    pts[i] = make_float4(x, y, z, sn_nc(x, y, z));
  }
  if (i < 2 * FPS_NBLK * SLOT_U64) slots[i] = KEY_NOTREADY;  // gen never matches t<2048
  if (i == 0) cidx[0] = 0;
}

// ---------------- kernel 1: FPS (cooperative, 4-block low-fan-in sync) ----------------

__global__ __launch_bounds__(FPS_NTHR, 1)
void k_fps(const float4* __restrict__ pts, int* __restrict__ cidx,
           unsigned long long* __restrict__ slots) {
  const int tid = threadIdx.x;
  const int bid = blockIdx.x;
  const int lane = tid & 63;
  const int wid = tid >> 6;
  const int base = bid * FPS_NTHR + tid;

  __shared__ F3 ldc[FPS_NTHR * PTS_PER];       // 153600 B; 12B stride -> conflict-free
  __shared__ unsigned long long s_w[8];
  __shared__ float s_wx, s_wy, s_wz;

  // min-dist state in registers (static indexing); coords live in LDS
  float m[PTS_PER];
  float bm = -1.0f; int bk = 0;
  {
    const float4 s = pts[0];
#pragma unroll
    for (int k = 0; k < PTS_PER; ++k) {
      const int g = base + k * FPS_STRIDE;
      const int gc = (g < NV) ? g : 0;
      const float4 p = pts[gc];
      F3 c; c.x = p.x; c.y = p.y; c.z = p.z;
      ldc[tid * PTS_PER + k] = c;
      m[k] = (g < NV) ? d2_nc(p.x, p.y, p.z, s.x, s.y, s.z) : 0.f;  // 0 never wins
      if (m[k] > bm) { bm = m[k]; bk = k; }   // ascending k == ascending idx
    }
  }
  __syncthreads();   // LDS mirror ready before first publish lookup

  for (int t = 0; t < NB - 1; ++t) {
    // ---- per-thread key, wave reduce, block reduce ----
    unsigned long long mk = pack_key(t, bm, (unsigned)(base + bk * FPS_STRIDE));
    mk = wave_max(mk);
    if (lane == 0) s_w[wid] = mk;
    __syncthreads();                                   // SYNC_A

    if (wid == 0) {
      // block-level final reduce (8 wave entries, 3 shfl levels)
      unsigned long long bkk = (lane < 8) ? s_w[lane] : 0ull;
      { unsigned long long o = __shfl_xor(bkk, 1, 64); if (o > bkk) bkk = o;
        o = __shfl_xor(bkk, 2, 64); if (o > bkk) bkk = o;
        o = __shfl_xor(bkk, 4, 64); if (o > bkk) bkk = o; }

      // ---- lane 0 publishes block winner (coords via LDS mirror) ----
      if (lane == 0) {
        const unsigned wbi = 0xFFFFu - (unsigned)(bkk & 0xFFFFull);
        const int rel = (int)wbi - bid * FPS_NTHR;     // = otid + ok*FPS_STRIDE
        const int otid = rel & (FPS_STRIDE - 1);
        const int ok = rel >> 11;                      // FPS_STRIDE = 2^11
        const F3 c = ldc[otid * PTS_PER + ok];
        const int sb = ((t & 1) * FPS_NBLK + bid) * SLOT_U64;
        const unsigned long long g64 = (unsigned long long)(unsigned)t << 32;
        __hip_atomic_store(&slots[sb + 0], bkk, __ATOMIC_RELAXED, __HIP_MEMORY_SCOPE_AGENT);
        __hip_atomic_store(&slots[sb + 1], g64 | __float_as_uint(c.x), __ATOMIC_RELAXED, __HIP_MEMORY_SCOPE_AGENT);
        __hip_atomic_store(&slots[sb + 2], g64 | __float_as_uint(c.y), __ATOMIC_RELAXED, __HIP_MEMORY_SCOPE_AGENT);
        __hip_atomic_store(&slots[sb + 3], g64 | __float_as_uint(c.z), __ATOMIC_RELAXED, __HIP_MEMORY_SCOPE_AGENT);
      }

      // ---- throttled poll of 4 padded slots (4 self-validating words each) ----
      unsigned long long v = 0ull;
      if (lane < 16) {
        const int w = lane & 3;                 // word within slot
        const int s = lane >> 2;                // slot (block)
        unsigned long long* addr = &slots[((t & 1) * FPS_NBLK + s) * SLOT_U64 + w];
        const unsigned want = (unsigned)t;
        for (;;) {
          v = __hip_atomic_load(addr, __ATOMIC_RELAXED, __HIP_MEMORY_SCOPE_AGENT);
          const unsigned g = (w == 0) ? (unsigned)(v >> 48) : (unsigned)(v >> 32);
          if (g == want) break;
          __builtin_amdgcn_s_sleep(1);          // backoff is load-bearing (r3/r7 evidence)
        }
      }
      // winner over the 4 key lanes (0,4,8,12): 2 shfl levels
      const bool iskey = (lane < 16) && ((lane & 3) == 0);
      unsigned long long kl = iskey ? v : 0ull;
      { unsigned long long o = __shfl_xor(kl, 4, 64); if (o > kl) kl = o;
        o = __shfl_xor(kl, 8, 64); if (o > kl) kl = o; }
      const unsigned long long ball = __ballot(iskey && (kl != 0ull) && (v == kl));
      const int src = __ffsll((long long)ball) - 1;    // key lane of winning slot
      const unsigned xb = (unsigned)__shfl((long long)v, src + 1, 64);
      const unsigned yb = (unsigned)__shfl((long long)v, src + 2, 64);
      const unsigned zb = (unsigned)__shfl((long long)v, src + 3, 64);
      if (lane == 0) {
        s_wx = __uint_as_float(xb);
        s_wy = __uint_as_float(yb);
        s_wz = __uint_as_float(zb);
        if (bid == 0) cidx[t + 1] = (int)(0xFFFFu - (unsigned)(kl & 0xFFFFull));
      }
    }
    __syncthreads();                                   // SYNC_B

    // ---- fused update + argmax for next step ----
    const float wx = s_wx, wy = s_wy, wz = s_wz;
    bm = -1.0f; bk = 0;
#pragma unroll
    for (int k = 0; k < PTS_PER; ++k) {
      const F3 p = ldc[tid * PTS_PER + k];
      const float nd = d2_nc(p.x, p.y, p.z, wx, wy, wz);
      m[k] = fminf(m[k], nd);
      if (m[k] > bm) { bm = m[k]; bk = k; }    // strict > keeps smallest idx on ties
    }
  }
}

// ---------------- kernel 2: per-centroid select + MLP + aggregate + global ----------------

__global__ __launch_bounds__(ROW_THR, 3)
void k_row(const float4* __restrict__ pts, const int* __restrict__ cidx,
           const float* __restrict__ W1, const float* __restrict__ b1,
           const float* __restrict__ W2, const float* __restrict__ b2,
           const float* __restrict__ Wg, const float* __restrict__ bg,
           float* __restrict__ out) {
  const int tid = threadIdx.x;
  const int row = blockIdx.x;

  __shared__ unsigned hist[1024];
  __shared__ unsigned psum[ROW_THR];
  __shared__ float cd[CAP];
  __shared__ int cidb[CAP];
  __shared__ float cd2[CAP2];
  __shared__ int ci2[CAP2];
  __shared__ int vlist[NKEEP];
  __shared__ float s_h[4][64];
  __shared__ float s_mred[4][64];
  __shared__ float s_agg[64];
  __shared__ int s_validn, s_k, s_mode, s_ncand, s_n2;

  const float4 c4 = pts[cidx[row]];

  for (int i = tid; i < 1024; i += ROW_THR) hist[i] = 0u;
  if (tid == 0) { s_ncand = 0; s_n2 = 0; }
  __syncthreads();

  // single global pass: compact ALL in-radius candidates + histogram
  for (int j = tid; j < NV; j += ROW_THR) {
    const float4 p = pts[j];
    const float t = tval_nc(c4.x, c4.y, c4.z, p.x, p.y, p.z, p.w);
    const float at = fabsf(t);
    if (at <= 0.0402f) {                 // conservative prefilter: d > 0.2004 otherwise
      const float d = sqrtf(at);
      if (d <= RADIUS_F) {
        const int pos = atomicAdd(&s_ncand, 1);
        if (pos < CAP) { cd[pos] = d; cidb[pos] = j; }
        int b = (int)(d * 5120.0f); if (b > 1023) b = 1023;
        atomicAdd(&hist[b], 1u);
      }
    }
  }
  __syncthreads();
  int n = s_ncand; if (n > CAP) n = CAP;

  {
    const int base = tid * 4;
    psum[tid] = hist[base] + hist[base + 1] + hist[base + 2] + hist[base + 3];
  }
  __syncthreads();
  if (tid == 0) {
    if (s_ncand <= NKEEP) {
      s_mode = 0; s_k = 1023;            // all in-radius points are valid
    } else {
      int cum = 0, kk = 1023;
      for (int i = 0; i < ROW_THR; ++i) {
        const int nc = cum + (int)psum[i];
        if (nc >= NKEEP) {
          int c2 = cum;
          for (int b = 0; b < 4; ++b) {
            c2 += (int)hist[i * 4 + b];
            if (c2 >= NKEEP) { kk = i * 4 + b; break; }
          }
          break;
        }
        cum = nc;
      }
      s_mode = 1; s_k = kk;
    }
  }
  __syncthreads();
  const int mode = s_mode, kbin = s_k;

  if (mode == 0) {
    if (tid < n) vlist[tid] = cidb[tid];       // n <= 65, all valid (max-agg is order-free)
    if (tid == 0) s_validn = n;
  } else {
    // sub-compact candidates with bin <= kbin from the LDS list (no global re-scan)
    for (int c = tid; c < n; c += ROW_THR) {
      const float d = cd[c];
      int b = (int)(d * 5120.0f); if (b > 1023) b = 1023;
      if (b <= kbin) {
        const int p = atomicAdd(&s_n2, 1);
        if (p < CAP2) { cd2[p] = d; ci2[p] = cidb[c]; }
      }
    }
    __syncthreads();
    int n2 = s_n2; if (n2 > CAP2) n2 = CAP2;
    // exact 65 smallest by (d, idx) lexicographic (matches lax.top_k tie-break)
    for (int c = tid; c < n2; c += ROW_THR) {
      const float dc = cd2[c]; const int ic = ci2[c];
      int r = 0;
      for (int j2 = 0; j2 < n2; ++j2) {
        const float dj = cd2[j2]; const int ij = ci2[j2];
        r += (int)((dj < dc) | ((dj == dc) & (ij < ic)));
      }
      if (r < NKEEP) vlist[r] = ic;
    }
    if (tid == 0) s_validn = NKEEP;
  }
  __syncthreads();
  const int nvld = s_validn;

  // MLP: 4 neighbor-groups x 64 channels
  const int ch = tid & 63, grp = tid >> 6;
  float amax = -INFINITY;
  for (int base = 0; base < nvld; base += 4) {
    const int slot = base + grp;
    if (slot < nvld) {
      const int j = vlist[slot];
      const float4 p = pts[j];
      const float f3 = p.x - c4.x, f4 = p.y - c4.y, f5 = p.z - c4.z;
      float hs = p.x * W1[ch] + p.y * W1[64 + ch] + p.z * W1[128 + ch]
               + f3 * W1[192 + ch] + f4 * W1[256 + ch] + f5 * W1[320 + ch];
      hs += b1[ch];
      s_h[grp][ch] = fmaxf(hs, 0.f);
    }
    __syncthreads();
    if (slot < nvld) {
      float acc = 0.f;
#pragma unroll 8
      for (int k2 = 0; k2 < 64; ++k2) acc += s_h[grp][k2] * W2[k2 * 64 + ch];
      acc += b2[ch];
      amax = fmaxf(amax, acc);
    }
    __syncthreads();
  }
  s_mred[grp][ch] = amax;
  __syncthreads();
  if (tid < 64) {
    s_agg[tid] = fmaxf(fmaxf(s_mred[0][tid], s_mred[1][tid]),
                       fmaxf(s_mred[2][tid], s_mred[3][tid]));
  }
  __syncthreads();
  if (tid < 128) {
    float acc = 0.f;
#pragma unroll 8
    for (int k2 = 0; k2 < 64; ++k2) acc += s_agg[k2] * Wg[k2 * 128 + tid];
    out[row * 128 + tid] = acc + bg[tid];
  }
}

// ---------------- launch ----------------

extern "C" void kernel_launch(void* const* d_in, const int* in_sizes, int n_in,
                              void* d_out, int out_size, void* d_ws, size_t ws_size,
                              hipStream_t stream) {
  const float* vtx = (const float*)d_in[0];
  const float* W1  = (const float*)d_in[1];
  const float* b1  = (const float*)d_in[2];
  const float* W2  = (const float*)d_in[3];
  const float* b2  = (const float*)d_in[4];
  const float* Wg  = (const float*)d_in[5];
  const float* bg  = (const float*)d_in[6];
  float* out = (float*)d_out;

  char* ws = (char*)d_ws;
  float4* pts = (float4*)ws;                                        // 800000 B
  int* cidx = (int*)(ws + 800000);                                  // 8192 B
  unsigned long long* slots = (unsigned long long*)(ws + 808192);   // 2*4*16*8 = 1024 B

  k_init<<<dim3((NV + 255) / 256), dim3(256), 0, stream>>>(vtx, pts, cidx, slots);

  void* args[] = { (void*)&pts, (void*)&cidx, (void*)&slots };
  (void)hipLaunchCooperativeKernel((void*)k_fps, dim3(FPS_NBLK), dim3(FPS_NTHR), args, 0, stream);

  k_row<<<dim3(NB), dim3(ROW_THR), 0, stream>>>(pts, cidx, W1, b1, W2, b2, Wg, bg, out);
}

// Round 10
// 5597.917 us; speedup vs baseline: 1.1229x; 1.1229x over previous
//
#include <hip/hip_runtime.h>
#include <math.h>

#define NV 50000
#define NB 2048
#define NKEEP 65          // K+1
#define RADIUS_F 0.2f

#define FPS_NBLK 8
#define FPS_NTHR 256
#define PTS_PER 25        // 8*256*25 = 51200 >= 50000
#define FPS_STRIDE (FPS_NBLK * FPS_NTHR)   // 2048
#define SLOT_U64 16       // 128 B per slot: each block's slot on its own LLC line

#define ROW_THR 256
#define CAP 5120          // all-in-radius candidate buffer per row (LDS)
#define CAP2 512          // sub-compacted (b<=kbin) buffer

// ---------------- no-contract arithmetic helpers ----------------

static __device__ __forceinline__ float sn_nc(float x, float y, float z) {
#pragma clang fp contract(off)
  return (x * x + y * y) + z * z;
}

static __device__ __forceinline__ float d2_nc(float ax, float ay, float az,
                                              float bx, float by, float bz) {
#pragma clang fp contract(off)
  float dx = ax - bx, dy = ay - by, dz = az - bz;
  return (dx * dx + dy * dy) + dz * dz;
}

static __device__ __forceinline__ float tval_nc(float cx, float cy, float cz,
                                                float px, float py, float pz,
                                                float pw) {
#pragma clang fp contract(off)
  float gd = (cx * px + cy * py) + cz * pz;
  return (pw - 2.0f * gd) + pw;
}

// ---------------- helpers ----------------

// word0 key = [gen:16 | d2bits:32 | (0xFFFF - idx):16]; d2>=0 so float bits are
// order-monotone; ties -> smaller idx wins (matches jnp.argmax)
static __device__ __forceinline__ unsigned long long pack_key(int gen, float v, unsigned idx) {
  return ((unsigned long long)(unsigned)gen << 48) |
         ((unsigned long long)__float_as_uint(v) << 16) |
         (unsigned long long)(0xFFFFu - idx);
}

static __device__ __forceinline__ unsigned long long wave_max(unsigned long long k) {
#pragma unroll
  for (int m = 1; m < 64; m <<= 1) {
    unsigned long long o = __shfl_xor(k, m, 64);
    if (o > k) k = o;
  }
  return k;
}

static __device__ __forceinline__ void slot_put(unsigned long long* p, unsigned long long v) {
  // RMW atomic: executes at the LLC (TCC) -> immediate device-wide visibility,
  // no write-combine latency (theory under test this round)
  (void)__hip_atomic_exchange(p, v, __ATOMIC_RELAXED, __HIP_MEMORY_SCOPE_AGENT);
}

#define KEY_NOTREADY 0xFFFF000000000000ull

// ---------------- kernel 0: pack (x,y,z,sn) + init slots ----------------

__global__ void k_init(const float* __restrict__ vtx, float4* __restrict__ pts,
                       int* __restrict__ cidx, unsigned long long* __restrict__ slots) {
  int i = blockIdx.x * blockDim.x + threadIdx.x;
  if (i < NV) {
    float x = vtx[3 * i], y = vtx[3 * i + 1], z = vtx[3 * i + 2];
    pts[i] = make_float4(x, y, z, sn_nc(x, y, z));
  }
  if (i < 2 * FPS_NBLK * SLOT_U64) slots[i] = KEY_NOTREADY;  // gen never matches t<2048
  if (i == 0) cidx[0] = 0;
}

// ---------------- kernel 1: FPS (r6 structure + atomic publish + padded slots) ----------------

__global__ __launch_bounds__(FPS_NTHR, 1)
void k_fps(const float4* __restrict__ pts, int* __restrict__ cidx,
           unsigned long long* __restrict__ slots) {
  const int tid = threadIdx.x;
  const int bid = blockIdx.x;
  const int lane = tid & 63;
  const int wid = tid >> 6;
  const int base = bid * FPS_NTHR + tid;

  // column-major coord mirror: lane-stride 1 dword -> conflict-free ds_read_b32
  __shared__ float ldx[PTS_PER * FPS_NTHR];
  __shared__ float ldy[PTS_PER * FPS_NTHR];
  __shared__ float ldz[PTS_PER * FPS_NTHR];
  __shared__ unsigned long long s_w[4];
  __shared__ float s_wx, s_wy, s_wz;

  // min-dist state in registers (static indexing); coords live in LDS
  float m[PTS_PER];
  float bm = -1.0f; int bk = 0;
  {
    const float4 s = pts[0];
#pragma unroll
    for (int k = 0; k < PTS_PER; ++k) {
      const int g = base + k * FPS_STRIDE;
      const int gc = (g < NV) ? g : 0;
      const float4 p = pts[gc];
      ldx[k * FPS_NTHR + tid] = p.x;
      ldy[k * FPS_NTHR + tid] = p.y;
      ldz[k * FPS_NTHR + tid] = p.z;
      m[k] = (g < NV) ? d2_nc(p.x, p.y, p.z, s.x, s.y, s.z) : 0.f;  // 0 never wins
      if (m[k] > bm) { bm = m[k]; bk = k; }   // ascending k == ascending idx
    }
  }
  __syncthreads();   // LDS mirror ready before first publish lookup

  for (int t = 0; t < NB - 1; ++t) {
    // ---- per-thread key, wave reduce, block reduce ----
    unsigned long long mk = pack_key(t, bm, (unsigned)(base + bk * FPS_STRIDE));
    mk = wave_max(mk);
    if (lane == 0) s_w[wid] = mk;
    __syncthreads();                                   // SYNC_A

    if (wid == 0) {
      // block-level final reduce (4 wave entries, 2 shfl levels)
      unsigned long long bkk = (lane < 4) ? s_w[lane] : 0ull;
      { unsigned long long o = __shfl_xor(bkk, 1, 64); if (o > bkk) bkk = o;
        o = __shfl_xor(bkk, 2, 64); if (o > bkk) bkk = o; }

      // ---- lane 0 publishes block winner (coords via LDS mirror, atomic puts) ----
      if (lane == 0) {
        const unsigned wbi = 0xFFFFu - (unsigned)(bkk & 0xFFFFull);
        const int rel = (int)wbi - bid * FPS_NTHR;     // = otid + ok*FPS_STRIDE
        const int otid = rel & (FPS_STRIDE - 1);
        const int ok = rel >> 11;                      // FPS_STRIDE = 2^11
        const float cx = ldx[ok * FPS_NTHR + otid];
        const float cy = ldy[ok * FPS_NTHR + otid];
        const float cz = ldz[ok * FPS_NTHR + otid];
        const int sb = ((t & 1) * FPS_NBLK + bid) * SLOT_U64;
        const unsigned long long g64 = (unsigned long long)(unsigned)t << 32;
        slot_put(&slots[sb + 1], g64 | __float_as_uint(cx));
        slot_put(&slots[sb + 2], g64 | __float_as_uint(cy));
        slot_put(&slots[sb + 3], g64 | __float_as_uint(cz));
        slot_put(&slots[sb + 0], bkk);
      }

      // ---- throttled poll of 8 padded slots (4 self-validating words each) ----
      unsigned long long v = 0ull;
      if (lane < 32) {
        const int w = lane & 3;                 // word within slot
        const int s = lane >> 2;                // slot (block)
        unsigned long long* addr = &slots[((t & 1) * FPS_NBLK + s) * SLOT_U64 + w];
        const unsigned want = (unsigned)t;
        for (;;) {
          v = __hip_atomic_load(addr, __ATOMIC_RELAXED, __HIP_MEMORY_SCOPE_AGENT);
          const unsigned g = (w == 0) ? (unsigned)(v >> 48) : (unsigned)(v >> 32);
          if (g == want) break;
          __builtin_amdgcn_s_sleep(1);          // backoff is load-bearing (r3/r7 evidence)
        }
      }
      // winner over the 8 key lanes (lanes 0,4,...,28): 3 shfl levels
      const bool iskey = (lane < 32) && ((lane & 3) == 0);
      unsigned long long kl = iskey ? v : 0ull;
      { unsigned long long o = __shfl_xor(kl, 4, 64);  if (o > kl) kl = o;
        o = __shfl_xor(kl, 8, 64);  if (o > kl) kl = o;
        o = __shfl_xor(kl, 16, 64); if (o > kl) kl = o; }
      const unsigned long long ball = __ballot(iskey && (kl != 0ull) && (v == kl));
      const int src = __ffsll((long long)ball) - 1;    // key lane of winning slot
      const unsigned xb = (unsigned)__shfl((long long)v, src + 1, 64);
      const unsigned yb = (unsigned)__shfl((long long)v, src + 2, 64);
      const unsigned zb = (unsigned)__shfl((long long)v, src + 3, 64);
      if (lane == 0) {
        s_wx = __uint_as_float(xb);
        s_wy = __uint_as_float(yb);
        s_wz = __uint_as_float(zb);
        if (bid == 0) cidx[t + 1] = (int)(0xFFFFu - (unsigned)(kl & 0xFFFFull));
      }
    }
    __syncthreads();                                   // SYNC_B

    // ---- fused update + argmax for next step (LDS coords, register m) ----
    const float wx = s_wx, wy = s_wy, wz = s_wz;
    bm = -1.0f; bk = 0;
#pragma unroll
    for (int k = 0; k < PTS_PER; ++k) {
      const float nd = d2_nc(ldx[k * FPS_NTHR + tid], ldy[k * FPS_NTHR + tid],
                             ldz[k * FPS_NTHR + tid], wx, wy, wz);
      m[k] = fminf(m[k], nd);
      if (m[k] > bm) { bm = m[k]; bk = k; }    // strict > keeps smallest idx on ties
    }
  }
}

// ---------------- kernel 2: per-centroid select + MLP + aggregate + global ----------------

__global__ __launch_bounds__(ROW_THR, 3)
void k_row(const float4* __restrict__ pts, const int* __restrict__ cidx,
           const float* __restrict__ W1, const float* __restrict__ b1,
           const float* __restrict__ W2, const float* __restrict__ b2,
           const float* __restrict__ Wg, const float* __restrict__ bg,
           float* __restrict__ out) {
  const int tid = threadIdx.x;
  const int row = blockIdx.x;

  __shared__ unsigned hist[1024];
  __shared__ unsigned psum[ROW_THR];
  __shared__ float cd[CAP];
  __shared__ int cidb[CAP];
  __shared__ float cd2[CAP2];
  __shared__ int ci2[CAP2];
  __shared__ int vlist[NKEEP];
  __shared__ float s_h[4][64];
  __shared__ float s_mred[4][64];
  __shared__ float s_agg[64];
  __shared__ int s_validn, s_k, s_mode, s_ncand, s_n2;

  const float4 c4 = pts[cidx[row]];

  for (int i = tid; i < 1024; i += ROW_THR) hist[i] = 0u;
  if (tid == 0) { s_ncand = 0; s_n2 = 0; }
  __syncthreads();

  // single global pass: compact ALL in-radius candidates + histogram
  for (int j = tid; j < NV; j += ROW_THR) {
    const float4 p = pts[j];
    const float t = tval_nc(c4.x, c4.y, c4.z, p.x, p.y, p.z, p.w);
    const float at = fabsf(t);
    if (at <= 0.0402f) {                 // conservative prefilter: d > 0.2004 otherwise
      const float d = sqrtf(at);
      if (d <= RADIUS_F) {
        const int pos = atomicAdd(&s_ncand, 1);
        if (pos < CAP) { cd[pos] = d; cidb[pos] = j; }
        int b = (int)(d * 5120.0f); if (b > 1023) b = 1023;
        atomicAdd(&hist[b], 1u);
      }
    }
  }
  __syncthreads();
  int n = s_ncand; if (n > CAP) n = CAP;

  {
    const int base = tid * 4;
    psum[tid] = hist[base] + hist[base + 1] + hist[base + 2] + hist[base + 3];
  }
  __syncthreads();
  if (tid == 0) {
    if (s_ncand <= NKEEP) {
      s_mode = 0; s_k = 1023;            // all in-radius points are valid
    } else {
      int cum = 0, kk = 1023;
      for (int i = 0; i < ROW_THR; ++i) {
        const int nc = cum + (int)psum[i];
        if (nc >= NKEEP) {
          int c2 = cum;
          for (int b = 0; b < 4; ++b) {
            c2 += (int)hist[i * 4 + b];
            if (c2 >= NKEEP) { kk = i * 4 + b; break; }
          }
          break;
        }
        cum = nc;
      }
      s_mode = 1; s_k = kk;
    }
  }
  __syncthreads();
  const int mode = s_mode, kbin = s_k;

  if (mode == 0) {
    if (tid < n) vlist[tid] = cidb[tid];       // n <= 65, all valid (max-agg is order-free)
    if (tid == 0) s_validn = n;
  } else {
    // sub-compact candidates with bin <= kbin from the LDS list (no global re-scan)
    for (int c = tid; c < n; c += ROW_THR) {
      const float d = cd[c];
      int b = (int)(d * 5120.0f); if (b > 1023) b = 1023;
      if (b <= kbin) {
        const int p = atomicAdd(&s_n2, 1);
        if (p < CAP2) { cd2[p] = d; ci2[p] = cidb[c]; }
      }
    }
    __syncthreads();
    int n2 = s_n2; if (n2 > CAP2) n2 = CAP2;
    // exact 65 smallest by (d, idx) lexicographic (matches lax.top_k tie-break)
    for (int c = tid; c < n2; c += ROW_THR) {
      const float dc = cd2[c]; const int ic = ci2[c];
      int r = 0;
      for (int j2 = 0; j2 < n2; ++j2) {
        const float dj = cd2[j2]; const int ij = ci2[j2];
        r += (int)((dj < dc) | ((dj == dc) & (ij < ic)));
      }
      if (r < NKEEP) vlist[r] = ic;
    }
    if (tid == 0) s_validn = NKEEP;
  }
  __syncthreads();
  const int nvld = s_validn;

  // MLP: 4 neighbor-groups x 64 channels
  const int ch = tid & 63, grp = tid >> 6;
  float amax = -INFINITY;
  for (int base = 0; base < nvld; base += 4) {
    const int slot = base + grp;
    if (slot < nvld) {
      const int j = vlist[slot];
      const float4 p = pts[j];
      const float f3 = p.x - c4.x, f4 = p.y - c4.y, f5 = p.z - c4.z;
      float hs = p.x * W1[ch] + p.y * W1[64 + ch] + p.z * W1[128 + ch]
               + f3 * W1[192 + ch] + f4 * W1[256 + ch] + f5 * W1[320 + ch];
      hs += b1[ch];
      s_h[grp][ch] = fmaxf(hs, 0.f);
    }
    __syncthreads();
    if (slot < nvld) {
      float acc = 0.f;
#pragma unroll 8
      for (int k2 = 0; k2 < 64; ++k2) acc += s_h[grp][k2] * W2[k2 * 64 + ch];
      acc += b2[ch];
      amax = fmaxf(amax, acc);
    }
    __syncthreads();
  }
  s_mred[grp][ch] = amax;
  __syncthreads();
  if (tid < 64) {
    s_agg[tid] = fmaxf(fmaxf(s_mred[0][tid], s_mred[1][tid]),
                       fmaxf(s_mred[2][tid], s_mred[3][tid]));
  }
  __syncthreads();
  if (tid < 128) {
    float acc = 0.f;
#pragma unroll 8
    for (int k2 = 0; k2 < 64; ++k2) acc += s_agg[k2] * Wg[k2 * 128 + tid];
    out[row * 128 + tid] = acc + bg[tid];
  }
}

// ---------------- launch ----------------

extern "C" void kernel_launch(void* const* d_in, const int* in_sizes, int n_in,
                              void* d_out, int out_size, void* d_ws, size_t ws_size,
                              hipStream_t stream) {
  const float* vtx = (const float*)d_in[0];
  const float* W1  = (const float*)d_in[1];
  const float* b1  = (const float*)d_in[2];
  const float* W2  = (const float*)d_in[3];
  const float* b2  = (const float*)d_in[4];
  const float* Wg  = (const float*)d_in[5];
  const float* bg  = (const float*)d_in[6];
  float* out = (float*)d_out;

  char* ws = (char*)d_ws;
  float4* pts = (float4*)ws;                                        // 800000 B
  int* cidx = (int*)(ws + 800000);                                  // 8192 B
  unsigned long long* slots = (unsigned long long*)(ws + 808192);   // 2*8*16*8 = 2048 B

  k_init<<<dim3((NV + 255) / 256), dim3(256), 0, stream>>>(vtx, pts, cidx, slots);

  void* args[] = { (void*)&pts, (void*)&cidx, (void*)&slots };
  (void)hipLaunchCooperativeKernel((void*)k_fps, dim3(FPS_NBLK), dim3(FPS_NTHR), args, 0, stream);

  k_row<<<dim3(NB), dim3(ROW_THR), 0, stream>>>(pts, cidx, W1, b1, W2, b2, Wg, bg, out);
}